// Round 12
// baseline (156.949 us; speedup 1.0000x reference)
//
#include <hip/hip_runtime.h>

#define N_NODES 100000
#define DIM 128
#define NS 10
#define SCALE (1.0f / 11.0f)
#define N16 ((size_t)N_NODES * 16)  // elems per 16-col slice plane (3.2 MB)
#define NSTRIP 3125                 // 3125 * 32 == 100000
#define NAGG 6256                   // 8 slices x 782 row-groups (128 rows each)

typedef unsigned int uint;
typedef unsigned short ushort;
typedef __attribute__((ext_vector_type(8))) short bf16x8;
typedef __attribute__((ext_vector_type(4))) float f32x4;

__device__ inline float bl(uint u) {  // bf16 bits (low 16) -> float
    union { uint x; float f; } c; c.x = u << 16; return c.f;
}
__device__ inline uint f2b(float x) {  // float -> bf16 bits (RNE)
    union { float f; uint u; } c; c.f = x;
    return (c.u + 0x7FFFu + ((c.u >> 16) & 1u)) >> 16;
}
__device__ inline void split8(const float* __restrict__ p, bf16x8& h, bf16x8& l) {
    const float4 a = *(const float4*)p;
    const float4 b = *(const float4*)(p + 4);
    const float xs[8] = {a.x, a.y, a.z, a.w, b.x, b.y, b.z, b.w};
#pragma unroll
    for (int j = 0; j < 8; ++j) {
        const uint hb = f2b(xs[j]);
        h[j] = (short)hb;
        l[j] = (short)f2b(xs[j] - bl(hb));
    }
}

// gemm1: FW1[r][e] = sum_k X[r][k]*W1[e][k]; bf16x3 MFMA (W split in-register
// from fp32 — no wsplit kernel). Output written into 8 column-slice planes
// [N][16] bf16 (plane e>>4): each plane is 3.2MB -> fits ONE XCD L2 for the
// downstream XCD-pinned gather. Wave's 64 lanes cover a contiguous 512B
// region per (bt, e-tile) -> coalesced. Also builds idx2[r][11] = {nodes[r],
// adj[nodes[r]][*]} for agg2b (overlapped with MFMA work across blocks).
__global__ __launch_bounds__(256, 2) void gemm1(const float* __restrict__ X,
                                                const float* __restrict__ W1,
                                                const int* __restrict__ adj,
                                                const int* __restrict__ nodes,
                                                ushort* __restrict__ C,
                                                int* __restrict__ idx2) {
    __shared__ __align__(16) ushort lds[8192];  // hi [0,4096), lo [4096,8192)
    const int t = threadIdx.x;
    const int lane = t & 63;
    const int wave = t >> 6;
    const int m16 = lane & 15;
    const int kq = lane >> 4;
    const int r0 = blockIdx.x * 32;  // 3125*32 == 100000

    // W1 fragments split in-register (A-operand; L2-hot across blocks)
    bf16x8 wh[2][4], wl[2][4];
#pragma unroll
    for (int c = 0; c < 2; ++c)
#pragma unroll
        for (int ks = 0; ks < 4; ++ks)
            split8(W1 + (size_t)((2 * wave + c) * 16 + m16) * DIM + ks * 32 + kq * 8,
                   wh[c][ks], wl[c][ks]);

    // X staging into fragment-layout LDS (hi/lo split at stage time)
    const int v0 = t, v1 = t + 256;
    const int ln0 = v0 & 63, ln1 = v1 & 63;
    {
        const float* s0 = X + (size_t)(r0 + (v0 >> 8) * 16 + (ln0 & 15)) * DIM +
                          ((v0 >> 6) & 3) * 32 + (ln0 >> 4) * 8;
        bf16x8 hi, lo;
        split8(s0, hi, lo);
        *(bf16x8*)(lds + (v0 >> 6) * 512 + ln0 * 8) = hi;
        *(bf16x8*)(lds + 4096 + (v0 >> 6) * 512 + ln0 * 8) = lo;
    }
    {
        const float* s1 = X + (size_t)(r0 + (v1 >> 8) * 16 + (ln1 & 15)) * DIM +
                          ((v1 >> 6) & 3) * 32 + (ln1 >> 4) * 8;
        bf16x8 hi, lo;
        split8(s1, hi, lo);
        *(bf16x8*)(lds + (v1 >> 6) * 512 + ln1 * 8) = hi;
        *(bf16x8*)(lds + 4096 + (v1 >> 6) * 512 + ln1 * 8) = lo;
    }

    // idx2 build for layer 2 (independent of LDS; overlaps across blocks)
    if (t < 32) {
        const int r = r0 + t;
        const int n = nodes[r];
        idx2[(size_t)r * 11] = n;
#pragma unroll
        for (int s = 0; s < NS; ++s)
            idx2[(size_t)r * 11 + 1 + s] = adj[(size_t)n * NS + s];
    }
    __syncthreads();

    f32x4 acc[2][2];  // [bt][c]
#pragma unroll
    for (int bt = 0; bt < 2; ++bt)
#pragma unroll
        for (int c = 0; c < 2; ++c) acc[bt][c] = (f32x4){0.f, 0.f, 0.f, 0.f};

#pragma unroll
    for (int ks = 0; ks < 4; ++ks) {
#pragma unroll
        for (int bt = 0; bt < 2; ++bt) {
            const int g = bt * 4 + ks;
            const bf16x8 xh = *(const bf16x8*)(lds + g * 512 + lane * 8);
            const bf16x8 xl = *(const bf16x8*)(lds + 4096 + g * 512 + lane * 8);
#pragma unroll
            for (int c = 0; c < 2; ++c) {
                acc[bt][c] = __builtin_amdgcn_mfma_f32_16x16x32_bf16(wh[c][ks], xh, acc[bt][c], 0, 0, 0);
                acc[bt][c] = __builtin_amdgcn_mfma_f32_16x16x32_bf16(wl[c][ks], xh, acc[bt][c], 0, 0, 0);
                acc[bt][c] = __builtin_amdgcn_mfma_f32_16x16x32_bf16(wh[c][ks], xl, acc[bt][c], 0, 0, 0);
            }
        }
    }

    // D: col(m16) = X-row, row(kq*4+reg) = e-within-tile.
    // e-tile (2*wave+c) == slice plane; in-plane elem = kq*4 + reg.
#pragma unroll
    for (int bt = 0; bt < 2; ++bt) {
        const size_t row = (size_t)(r0 + bt * 16 + m16);
#pragma unroll
        for (int c = 0; c < 2; ++c) {
            uint2 w;
            w.x = f2b(acc[bt][c][0]) | (f2b(acc[bt][c][1]) << 16);
            w.y = f2b(acc[bt][c][2]) | (f2b(acc[bt][c][3]) << 16);
            *(uint2*)(C + (size_t)(2 * wave + c) * N16 + row * 16 + kq * 4) = w;
        }
    }
}

// agg1: H[i] = relu(mean(FW[{i} U adj[i]])), per 16-col slice plane.
// slice = blockIdx & 7 -> pins all gathers of plane s to XCD s (round-robin
// block->XCD dispatch); plane = 3.2MB -> L2-resident. 128 rows/block,
// 2 threads/row (16B each), 11 x uint4 gathers per thread.
__global__ __launch_bounds__(256) void agg1(const ushort* __restrict__ FW,
                                            const int* __restrict__ adj,
                                            ushort* __restrict__ H) {
    __shared__ int idx[1280];
    const int t = threadIdx.x;
    const int s = blockIdx.x & 7;         // slice == XCD
    const int r0 = (blockIdx.x >> 3) * 128;
    for (int l = t; l < 1280; l += 256) {
        const size_t gi = (size_t)r0 * NS + l;  // adj rows contiguous
        idx[l] = (gi < (size_t)N_NODES * NS) ? adj[gi] : 0;
    }
    __syncthreads();
    const int ri = t >> 1;
    const int hf = t & 1;
    const int row = r0 + ri;
    if (row >= N_NODES) return;
    const ushort* Fp = FW + (size_t)s * N16 + hf * 8;
    uint4 u[11];
    u[0] = *(const uint4*)(Fp + (size_t)row * 16);
#pragma unroll
    for (int q = 0; q < NS; ++q)
        u[1 + q] = *(const uint4*)(Fp + (size_t)idx[ri * NS + q] * 16);
    float a[8];
#pragma unroll
    for (int k = 0; k < 8; ++k) a[k] = 0.f;
#pragma unroll
    for (int q = 0; q < 11; ++q) {
        a[0] += bl(u[q].x); a[1] += bl(u[q].x >> 16);
        a[2] += bl(u[q].y); a[3] += bl(u[q].y >> 16);
        a[4] += bl(u[q].z); a[5] += bl(u[q].z >> 16);
        a[6] += bl(u[q].w); a[7] += bl(u[q].w >> 16);
    }
    uint4 w;
    w.x = f2b(fmaxf(a[0] * SCALE, 0.f)) | (f2b(fmaxf(a[1] * SCALE, 0.f)) << 16);
    w.y = f2b(fmaxf(a[2] * SCALE, 0.f)) | (f2b(fmaxf(a[3] * SCALE, 0.f)) << 16);
    w.z = f2b(fmaxf(a[4] * SCALE, 0.f)) | (f2b(fmaxf(a[5] * SCALE, 0.f)) << 16);
    w.w = f2b(fmaxf(a[6] * SCALE, 0.f)) | (f2b(fmaxf(a[7] * SCALE, 0.f)) << 16);
    *(uint4*)(H + (size_t)s * N16 + (size_t)row * 16 + hf * 8) = w;
}

// agg2b: P[i] = mean(H[idx2[i][*]]) (no relu), same XCD-pinned slice scheme.
// idx2 (built by gemm1) read contiguously — no repeated random adj walk.
__global__ __launch_bounds__(256) void agg2b(const ushort* __restrict__ H,
                                             const int* __restrict__ idx2,
                                             ushort* __restrict__ P) {
    __shared__ int idx[1408];
    const int t = threadIdx.x;
    const int s = blockIdx.x & 7;
    const int r0 = (blockIdx.x >> 3) * 128;
    for (int l = t; l < 1408; l += 256) {
        const size_t gi = (size_t)r0 * 11 + l;
        idx[l] = (gi < (size_t)N_NODES * 11) ? idx2[gi] : 0;
    }
    __syncthreads();
    const int ri = t >> 1;
    const int hf = t & 1;
    const int row = r0 + ri;
    if (row >= N_NODES) return;
    const ushort* Hp = H + (size_t)s * N16 + hf * 8;
    uint4 u[11];
#pragma unroll
    for (int q = 0; q < 11; ++q)
        u[q] = *(const uint4*)(Hp + (size_t)idx[ri * 11 + q] * 16);
    float a[8];
#pragma unroll
    for (int k = 0; k < 8; ++k) a[k] = 0.f;
#pragma unroll
    for (int q = 0; q < 11; ++q) {
        a[0] += bl(u[q].x); a[1] += bl(u[q].x >> 16);
        a[2] += bl(u[q].y); a[3] += bl(u[q].y >> 16);
        a[4] += bl(u[q].z); a[5] += bl(u[q].z >> 16);
        a[6] += bl(u[q].w); a[7] += bl(u[q].w >> 16);
    }
    uint4 w;
    w.x = f2b(a[0] * SCALE) | (f2b(a[1] * SCALE) << 16);
    w.y = f2b(a[2] * SCALE) | (f2b(a[3] * SCALE) << 16);
    w.z = f2b(a[4] * SCALE) | (f2b(a[5] * SCALE) << 16);
    w.w = f2b(a[6] * SCALE) | (f2b(a[7] * SCALE) << 16);
    *(uint4*)(P + (size_t)s * N16 + (size_t)row * 16 + hf * 8) = w;
}

// gemm2t: out[e][b] = relu(sum_k P[b][k]*W2[e][k]); P read from slice planes
// into LDS fragment layout (linear write, 0 conflicts); W2 split in-register.
// acc regs = 4 consecutive b at fixed e -> coalesced float4 stores to [E][B].
__global__ __launch_bounds__(256, 2) void gemm2t(const ushort* __restrict__ P,
                                                 const float* __restrict__ W2,
                                                 float* __restrict__ out) {
    __shared__ __align__(16) ushort lds[4096];  // 8 groups x 64 lanes x 8 bf16
    const int t = threadIdx.x;
    const int lane = t & 63;
    const int wave = t >> 6;
    const int m16 = lane & 15;
    const int kq = lane >> 4;
    const int r0 = blockIdx.x * 32;

    // slot v: bt=v>>8, ksq=(v>>6)&3, ln=v&63 holds P[row][k0..k0+8),
    // row = r0+bt*16+(ln&15), k0 = ksq*32+(ln>>4)*8 -> slice k0>>4, off (k0&15)
#pragma unroll
    for (int i = 0; i < 2; ++i) {
        const int v = t + i * 256;
        const int ln = v & 63;
        const int ksq = (v >> 6) & 3;
        const int row = r0 + (v >> 8) * 16 + (ln & 15);
        const int k0 = ksq * 32 + (ln >> 4) * 8;
        const bf16x8 pv = *(const bf16x8*)(P + (size_t)(k0 >> 4) * N16 +
                                           (size_t)row * 16 + (k0 & 15));
        *(bf16x8*)(lds + (v >> 6) * 512 + ln * 8) = pv;
    }

    bf16x8 wh[2][4], wl[2][4];
#pragma unroll
    for (int c = 0; c < 2; ++c)
#pragma unroll
        for (int ks = 0; ks < 4; ++ks)
            split8(W2 + (size_t)((2 * wave + c) * 16 + m16) * DIM + ks * 32 + kq * 8,
                   wh[c][ks], wl[c][ks]);
    __syncthreads();

    f32x4 acc[2][2];  // [bt][c]
#pragma unroll
    for (int bt = 0; bt < 2; ++bt)
#pragma unroll
        for (int c = 0; c < 2; ++c) acc[bt][c] = (f32x4){0.f, 0.f, 0.f, 0.f};

#pragma unroll
    for (int ks = 0; ks < 4; ++ks) {
#pragma unroll
        for (int bt = 0; bt < 2; ++bt) {
            const bf16x8 pa = *(const bf16x8*)(lds + (bt * 4 + ks) * 512 + lane * 8);
#pragma unroll
            for (int c = 0; c < 2; ++c) {
                acc[bt][c] = __builtin_amdgcn_mfma_f32_16x16x32_bf16(pa, wh[c][ks], acc[bt][c], 0, 0, 0);
                acc[bt][c] = __builtin_amdgcn_mfma_f32_16x16x32_bf16(pa, wl[c][ks], acc[bt][c], 0, 0, 0);
            }
        }
    }

    // D: col(m16) = e (B-side), row(kq*4+reg) = b (A-side)
#pragma unroll
    for (int bt = 0; bt < 2; ++bt) {
        const int b = r0 + bt * 16 + kq * 4;
#pragma unroll
        for (int c = 0; c < 2; ++c) {
            const int e = (2 * wave + c) * 16 + m16;
            float4 v;
            v.x = fmaxf(acc[bt][c][0], 0.f);
            v.y = fmaxf(acc[bt][c][1], 0.f);
            v.z = fmaxf(acc[bt][c][2], 0.f);
            v.w = fmaxf(acc[bt][c][3], 0.f);
            *(float4*)(out + (size_t)e * N_NODES + b) = v;
        }
    }
}

extern "C" void kernel_launch(void* const* d_in, const int* in_sizes, int n_in,
                              void* d_out, int out_size, void* d_ws, size_t ws_size,
                              hipStream_t stream) {
    const float* features = (const float*)d_in[0];
    const float* W1 = (const float*)d_in[1];
    const float* W2 = (const float*)d_in[2];
    const int* adj = (const int*)d_in[3];
    const int* nodes = (const int*)d_in[4];
    float* out = (float*)d_out;

    ushort* fw = (ushort*)d_ws;        // FW1 slice planes (25.6 MB)
    ushort* h1 = fw + N16 * 8;         // h1 slice planes (25.6 MB)
    ushort* pp = h1 + N16 * 8;         // P slice planes (25.6 MB)
    int* idx2 = (int*)(pp + N16 * 8);  // [N][11] layer-2 indices (4.4 MB)

    // FW1 = features @ W1^T (slice planes) + idx2 build
    gemm1<<<NSTRIP, 256, 0, stream>>>(features, W1, adj, nodes, fw, idx2);
    // h1 = relu(mean(FW1[self U adj])), XCD-pinned per-slice gathers
    agg1<<<NAGG, 256, 0, stream>>>(fw, adj, h1);
    // P = mean(h1[nodes U adj[nodes]]), XCD-pinned per-slice gathers
    agg2b<<<NAGG, 256, 0, stream>>>(h1, idx2, pp);
    // out[e][b] = relu(P @ W2^T), coalesced transposed store
    gemm2t<<<NSTRIP, 256, 0, stream>>>(pp, W2, out);
}

// Round 13
// 152.554 us; speedup vs baseline: 1.0288x; 1.0288x over previous
//
#include <hip/hip_runtime.h>

#define N_NODES 100000
#define DIM 128
#define NS 10
#define SCALE (1.0f / 11.0f)
#define NE2 ((size_t)N_NODES * 64)  // elems per 64-col plane (12.8 MB)
#define NSTRIP 3125                 // 3125 * 32 == 100000

typedef unsigned int uint;
typedef unsigned short ushort;
typedef __attribute__((ext_vector_type(8))) short bf16x8;
typedef __attribute__((ext_vector_type(4))) float f32x4;

__device__ inline float bl(uint u) {  // bf16 bits (low 16) -> float
    union { uint x; float f; } c; c.x = u << 16; return c.f;
}
__device__ inline uint f2b(float x) {  // float -> bf16 bits (RNE)
    union { float f; uint u; } c; c.f = x;
    return (c.u + 0x7FFFu + ((c.u >> 16) & 1u)) >> 16;
}
__device__ inline void split8(const float* __restrict__ p, bf16x8& h, bf16x8& l) {
    const float4 a = *(const float4*)p;
    const float4 b = *(const float4*)(p + 4);
    const float xs[8] = {a.x, a.y, a.z, a.w, b.x, b.y, b.z, b.w};
#pragma unroll
    for (int j = 0; j < 8; ++j) {
        const uint hb = f2b(xs[j]);
        h[j] = (short)hb;
        l[j] = (short)f2b(xs[j] - bl(hb));
    }
}

// gemm1: FW1[r][e] = sum_k X[r][k]*W1[e][k]; bf16x3 MFMA (W1 split to hi/lo
// bf16 in-register — no wsplit kernel). Output: two 64-col planes [N][64]
// (row = one 128B line, the gather-optimal layout). Also builds
// idx2[r][11] = {nodes[r], adj[nodes[r]][*]} for agg2b.
__global__ __launch_bounds__(256, 2) void gemm1(const float* __restrict__ X,
                                                const float* __restrict__ W1,
                                                const int* __restrict__ adj,
                                                const int* __restrict__ nodes,
                                                ushort* __restrict__ C,
                                                int* __restrict__ idx2) {
    __shared__ __align__(16) ushort lds[8192];  // hi [0,4096), lo [4096,8192)
    const int t = threadIdx.x;
    const int lane = t & 63;
    const int wave = t >> 6;
    const int m16 = lane & 15;
    const int kq = lane >> 4;
    const int r0 = blockIdx.x * 32;  // 3125*32 == 100000, no guards

    // W1 fragments (A-operand), split in-register; L2-hot across blocks
    bf16x8 wh[2][4], wl[2][4];
#pragma unroll
    for (int c = 0; c < 2; ++c)
#pragma unroll
        for (int ks = 0; ks < 4; ++ks)
            split8(W1 + (size_t)((2 * wave + c) * 16 + m16) * DIM + ks * 32 + kq * 8,
                   wh[c][ks], wl[c][ks]);

    // X staged to LDS in fragment layout (hi/lo split at stage time)
    const int v0 = t, v1 = t + 256;
    const int ln0 = v0 & 63, ln1 = v1 & 63;
    {
        const float* s0 = X + (size_t)(r0 + (v0 >> 8) * 16 + (ln0 & 15)) * DIM +
                          ((v0 >> 6) & 3) * 32 + (ln0 >> 4) * 8;
        bf16x8 hi, lo;
        split8(s0, hi, lo);
        *(bf16x8*)(lds + (v0 >> 6) * 512 + ln0 * 8) = hi;
        *(bf16x8*)(lds + 4096 + (v0 >> 6) * 512 + ln0 * 8) = lo;
    }
    {
        const float* s1 = X + (size_t)(r0 + (v1 >> 8) * 16 + (ln1 & 15)) * DIM +
                          ((v1 >> 6) & 3) * 32 + (ln1 >> 4) * 8;
        bf16x8 hi, lo;
        split8(s1, hi, lo);
        *(bf16x8*)(lds + (v1 >> 6) * 512 + ln1 * 8) = hi;
        *(bf16x8*)(lds + 4096 + (v1 >> 6) * 512 + ln1 * 8) = lo;
    }

    // idx2 build for layer 2 (overlaps with staging/MFMA across blocks)
    if (t < 32) {
        const int r = r0 + t;
        const int n = nodes[r];
        idx2[(size_t)r * 11] = n;
#pragma unroll
        for (int s = 0; s < NS; ++s)
            idx2[(size_t)r * 11 + 1 + s] = adj[(size_t)n * NS + s];
    }
    __syncthreads();

    f32x4 acc[2][2];  // [bt][c]
#pragma unroll
    for (int bt = 0; bt < 2; ++bt)
#pragma unroll
        for (int c = 0; c < 2; ++c) acc[bt][c] = (f32x4){0.f, 0.f, 0.f, 0.f};

#pragma unroll
    for (int ks = 0; ks < 4; ++ks) {
#pragma unroll
        for (int bt = 0; bt < 2; ++bt) {
            const int g = bt * 4 + ks;
            const bf16x8 xh = *(const bf16x8*)(lds + g * 512 + lane * 8);
            const bf16x8 xl = *(const bf16x8*)(lds + 4096 + g * 512 + lane * 8);
#pragma unroll
            for (int c = 0; c < 2; ++c) {
                acc[bt][c] = __builtin_amdgcn_mfma_f32_16x16x32_bf16(wh[c][ks], xh, acc[bt][c], 0, 0, 0);
                acc[bt][c] = __builtin_amdgcn_mfma_f32_16x16x32_bf16(wl[c][ks], xh, acc[bt][c], 0, 0, 0);
                acc[bt][c] = __builtin_amdgcn_mfma_f32_16x16x32_bf16(wh[c][ks], xl, acc[bt][c], 0, 0, 0);
            }
        }
    }

    // D: col(m16)=X-row, row(kq*4+reg)=e. Global e = 32*wave+16*c+4*kq ->
    // plane = wave>>1, in-plane col = 32*(wave&1)+16*c+4*kq.
#pragma unroll
    for (int bt = 0; bt < 2; ++bt) {
        const size_t row = (size_t)(r0 + bt * 16 + m16);
#pragma unroll
        for (int c = 0; c < 2; ++c) {
            uint2 w;
            w.x = f2b(acc[bt][c][0]) | (f2b(acc[bt][c][1]) << 16);
            w.y = f2b(acc[bt][c][2]) | (f2b(acc[bt][c][3]) << 16);
            *(uint2*)(C + (size_t)(wave >> 1) * NE2 + row * 64 +
                      (2 * (wave & 1) + c) * 16 + kq * 4) = w;
        }
    }
}

// agg1: H[i] = relu(mean(FW[{i} U adj[i]])); two [N][64] planes (row = one
// 128B line, 16 lanes x uint2 = full-line transactions). r9-proven 41us wall.
__global__ __launch_bounds__(256) void agg1(const ushort* __restrict__ FW,
                                            const int* __restrict__ adj,
                                            ushort* __restrict__ H) {
    __shared__ int idx_lds[320];
    const int t = threadIdx.x;
    const int r0 = blockIdx.x * 32;  // 3125 blocks
    for (int l = t; l < 320; l += 256)
        idx_lds[l] = adj[(size_t)r0 * NS + l];  // rows r0..r0+31 contiguous
    __syncthreads();
    const int team = t >> 4;
    const int j = t & 15;
    const int ri0 = team * 2, ri1 = team * 2 + 1;
#pragma unroll
    for (int p = 0; p < 2; ++p) {
        const ushort* FWp = FW + (size_t)p * NE2;
        ushort* Hp = H + (size_t)p * NE2;
        uint2 u0[11], u1[11];
        u0[0] = ((const uint2*)(FWp + (size_t)(r0 + ri0) * 64))[j];
#pragma unroll
        for (int s = 0; s < NS; ++s)
            u0[1 + s] = ((const uint2*)(FWp + (size_t)idx_lds[ri0 * NS + s] * 64))[j];
        u1[0] = ((const uint2*)(FWp + (size_t)(r0 + ri1) * 64))[j];
#pragma unroll
        for (int s = 0; s < NS; ++s)
            u1[1 + s] = ((const uint2*)(FWp + (size_t)idx_lds[ri1 * NS + s] * 64))[j];
        float a0 = 0.f, a1 = 0.f, a2 = 0.f, a3 = 0.f;
        float b0 = 0.f, b1 = 0.f, b2 = 0.f, b3 = 0.f;
#pragma unroll
        for (int s = 0; s < 11; ++s) {
            a0 += bl(u0[s].x); a1 += bl(u0[s].x >> 16);
            a2 += bl(u0[s].y); a3 += bl(u0[s].y >> 16);
            b0 += bl(u1[s].x); b1 += bl(u1[s].x >> 16);
            b2 += bl(u1[s].y); b3 += bl(u1[s].y >> 16);
        }
        uint2 w;
        w.x = f2b(fmaxf(a0 * SCALE, 0.f)) | (f2b(fmaxf(a1 * SCALE, 0.f)) << 16);
        w.y = f2b(fmaxf(a2 * SCALE, 0.f)) | (f2b(fmaxf(a3 * SCALE, 0.f)) << 16);
        ((uint2*)(Hp + (size_t)(r0 + ri0) * 64))[j] = w;
        w.x = f2b(fmaxf(b0 * SCALE, 0.f)) | (f2b(fmaxf(b1 * SCALE, 0.f)) << 16);
        w.y = f2b(fmaxf(b2 * SCALE, 0.f)) | (f2b(fmaxf(b3 * SCALE, 0.f)) << 16);
        ((uint2*)(Hp + (size_t)(r0 + ri1) * 64))[j] = w;
    }
}

// agg2b: P[i] = mean(H[idx2[i][*]]) (no relu); idx2 prebuilt by gemm1 ->
// the per-block index stage is one contiguous read, no random adj walk.
__global__ __launch_bounds__(256) void agg2b(const ushort* __restrict__ H,
                                             const int* __restrict__ idx2,
                                             ushort* __restrict__ P) {
    __shared__ int idx_lds[352];
    const int t = threadIdx.x;
    const int r0 = blockIdx.x * 32;  // 3125 blocks
    for (int l = t; l < 352; l += 256)
        idx_lds[l] = idx2[(size_t)r0 * 11 + l];  // r0*11+352 <= N*11, no OOB
    __syncthreads();
    const int team = t >> 4;
    const int j = t & 15;
    const int ri0 = team * 2, ri1 = team * 2 + 1;
#pragma unroll
    for (int p = 0; p < 2; ++p) {
        const ushort* Hp = H + (size_t)p * NE2;
        ushort* Pp = P + (size_t)p * NE2;
        uint2 u0[11], u1[11];
#pragma unroll
        for (int s = 0; s < 11; ++s)
            u0[s] = ((const uint2*)(Hp + (size_t)idx_lds[ri0 * 11 + s] * 64))[j];
#pragma unroll
        for (int s = 0; s < 11; ++s)
            u1[s] = ((const uint2*)(Hp + (size_t)idx_lds[ri1 * 11 + s] * 64))[j];
        float a0 = 0.f, a1 = 0.f, a2 = 0.f, a3 = 0.f;
        float b0 = 0.f, b1 = 0.f, b2 = 0.f, b3 = 0.f;
#pragma unroll
        for (int s = 0; s < 11; ++s) {
            a0 += bl(u0[s].x); a1 += bl(u0[s].x >> 16);
            a2 += bl(u0[s].y); a3 += bl(u0[s].y >> 16);
            b0 += bl(u1[s].x); b1 += bl(u1[s].x >> 16);
            b2 += bl(u1[s].y); b3 += bl(u1[s].y >> 16);
        }
        uint2 w;
        w.x = f2b(a0 * SCALE) | (f2b(a1 * SCALE) << 16);
        w.y = f2b(a2 * SCALE) | (f2b(a3 * SCALE) << 16);
        ((uint2*)(Pp + (size_t)(r0 + ri0) * 64))[j] = w;
        w.x = f2b(b0 * SCALE) | (f2b(b1 * SCALE) << 16);
        w.y = f2b(b2 * SCALE) | (f2b(b3 * SCALE) << 16);
        ((uint2*)(Pp + (size_t)(r0 + ri1) * 64))[j] = w;
    }
}

// gemm2t: out[e][b] = relu(sum_k P[b][k]*W2[e][k]); P from the two 64-col
// planes into LDS fragment layout (linear write, 0 conflicts); W2 split
// in-register (B-operand). acc regs = 4 consecutive b -> float4 stores.
__global__ __launch_bounds__(256, 2) void gemm2t(const ushort* __restrict__ P,
                                                 const float* __restrict__ W2,
                                                 float* __restrict__ out) {
    __shared__ __align__(16) ushort lds[4096];  // 8 groups x 64 lanes x 8 bf16
    const int t = threadIdx.x;
    const int lane = t & 63;
    const int wave = t >> 6;
    const int m16 = lane & 15;
    const int kq = lane >> 4;
    const int r0 = blockIdx.x * 32;

    // slot v: bt=v>>8, ksq=(v>>6)&3, ln=v&63; row=r0+bt*16+(ln&15);
    // k0=ksq*32+(ln>>4)*8 -> plane=ksq>>1, in-plane col=(ksq&1)*32+(ln>>4)*8
#pragma unroll
    for (int i = 0; i < 2; ++i) {
        const int v = t + i * 256;
        const int ln = v & 63;
        const int ksq = (v >> 6) & 3;
        const ushort* s = P + (size_t)(ksq >> 1) * NE2 +
                          (size_t)(r0 + (v >> 8) * 16 + (ln & 15)) * 64 +
                          (ksq & 1) * 32 + (ln >> 4) * 8;
        *(bf16x8*)(lds + (v >> 6) * 512 + ln * 8) = *(const bf16x8*)(s);
    }

    bf16x8 wh[2][4], wl[2][4];
#pragma unroll
    for (int c = 0; c < 2; ++c)
#pragma unroll
        for (int ks = 0; ks < 4; ++ks)
            split8(W2 + (size_t)((2 * wave + c) * 16 + m16) * DIM + ks * 32 + kq * 8,
                   wh[c][ks], wl[c][ks]);
    __syncthreads();

    f32x4 acc[2][2];  // [bt][c]
#pragma unroll
    for (int bt = 0; bt < 2; ++bt)
#pragma unroll
        for (int c = 0; c < 2; ++c) acc[bt][c] = (f32x4){0.f, 0.f, 0.f, 0.f};

#pragma unroll
    for (int ks = 0; ks < 4; ++ks) {
#pragma unroll
        for (int bt = 0; bt < 2; ++bt) {
            const bf16x8 pa = *(const bf16x8*)(lds + (bt * 4 + ks) * 512 + lane * 8);
#pragma unroll
            for (int c = 0; c < 2; ++c) {
                acc[bt][c] = __builtin_amdgcn_mfma_f32_16x16x32_bf16(pa, wh[c][ks], acc[bt][c], 0, 0, 0);
                acc[bt][c] = __builtin_amdgcn_mfma_f32_16x16x32_bf16(pa, wl[c][ks], acc[bt][c], 0, 0, 0);
            }
        }
    }

    // D: col(m16) = e (B-side), row(kq*4+reg) = b (A-side)
#pragma unroll
    for (int bt = 0; bt < 2; ++bt) {
        const int b = r0 + bt * 16 + kq * 4;
#pragma unroll
        for (int c = 0; c < 2; ++c) {
            const int e = (2 * wave + c) * 16 + m16;
            float4 v;
            v.x = fmaxf(acc[bt][c][0], 0.f);
            v.y = fmaxf(acc[bt][c][1], 0.f);
            v.z = fmaxf(acc[bt][c][2], 0.f);
            v.w = fmaxf(acc[bt][c][3], 0.f);
            *(float4*)(out + (size_t)e * N_NODES + b) = v;
        }
    }
}

extern "C" void kernel_launch(void* const* d_in, const int* in_sizes, int n_in,
                              void* d_out, int out_size, void* d_ws, size_t ws_size,
                              hipStream_t stream) {
    const float* features = (const float*)d_in[0];
    const float* W1 = (const float*)d_in[1];
    const float* W2 = (const float*)d_in[2];
    const int* adj = (const int*)d_in[3];
    const int* nodes = (const int*)d_in[4];
    float* out = (float*)d_out;

    const size_t NE = (size_t)N_NODES * DIM;  // 12.8M elems (= 2 planes)
    ushort* fw = (ushort*)d_ws;        // FW1 planes; later reused as P (25.6 MB)
    ushort* h1 = fw + NE;              // h1 planes (25.6 MB)
    int* idx2 = (int*)(h1 + NE);       // [N][11] layer-2 indices (4.4 MB)

    // FW1 = features @ W1^T (in-register W split) + idx2 build
    gemm1<<<NSTRIP, 256, 0, stream>>>(features, W1, adj, nodes, fw, idx2);
    // h1 = relu(mean(FW1[self U adj]))
    agg1<<<NSTRIP, 256, 0, stream>>>(fw, adj, h1);
    // P = mean(h1[idx2]) (reuses fw buffer)
    agg2b<<<NSTRIP, 256, 0, stream>>>(h1, idx2, fw);
    // out[e][b] = relu(P @ W2^T), coalesced transposed store
    gemm2t<<<NSTRIP, 256, 0, stream>>>(fw, W2, out);
}

// Round 14
// 151.454 us; speedup vs baseline: 1.0363x; 1.0073x over previous
//
#include <hip/hip_runtime.h>

#define N_NODES 100000
#define DIM 128
#define NS 10
#define SCALE (1.0f / 11.0f)
#define NE2 ((size_t)N_NODES * 64)  // elems per 64-col plane (12.8 MB)
#define NSTRIP 3125                 // 3125 * 32 == 100000

typedef unsigned int uint;
typedef unsigned short ushort;
typedef __attribute__((ext_vector_type(8))) short bf16x8;
typedef __attribute__((ext_vector_type(4))) float f32x4;

__device__ inline float bl(uint u) {  // bf16 bits (low 16) -> float
    union { uint x; float f; } c; c.x = u << 16; return c.f;
}
__device__ inline uint f2b(float x) {  // float -> bf16 bits (RNE)
    union { float f; uint u; } c; c.f = x;
    return (c.u + 0x7FFFu + ((c.u >> 16) & 1u)) >> 16;
}
__device__ inline void split8(const float* __restrict__ p, bf16x8& h, bf16x8& l) {
    const float4 a = *(const float4*)p;
    const float4 b = *(const float4*)(p + 4);
    const float xs[8] = {a.x, a.y, a.z, a.w, b.x, b.y, b.z, b.w};
#pragma unroll
    for (int j = 0; j < 8; ++j) {
        const uint hb = f2b(xs[j]);
        h[j] = (short)hb;
        l[j] = (short)f2b(xs[j] - bl(hb));
    }
}

// gemm1: FW1[r][e] = sum_k X[r][k]*W1[e][k]; bf16x3 MFMA (W1 split to hi/lo
// bf16 in-register). Output: two 64-col planes [N][64] (row = one 128B line).
// NO serial index build here (r13 lesson: a dependent random-load chain in a
// 2-blocks/CU MFMA kernel stalls the barrier, +33us).
__global__ __launch_bounds__(256, 2) void gemm1(const float* __restrict__ X,
                                                const float* __restrict__ W1,
                                                ushort* __restrict__ C) {
    __shared__ __align__(16) ushort lds[8192];  // hi [0,4096), lo [4096,8192)
    const int t = threadIdx.x;
    const int lane = t & 63;
    const int wave = t >> 6;
    const int m16 = lane & 15;
    const int kq = lane >> 4;
    const int r0 = blockIdx.x * 32;  // 3125*32 == 100000, no guards

    // W1 fragments (A-operand), split in-register; L2-hot across blocks
    bf16x8 wh[2][4], wl[2][4];
#pragma unroll
    for (int c = 0; c < 2; ++c)
#pragma unroll
        for (int ks = 0; ks < 4; ++ks)
            split8(W1 + (size_t)((2 * wave + c) * 16 + m16) * DIM + ks * 32 + kq * 8,
                   wh[c][ks], wl[c][ks]);

    // X staged to LDS in fragment layout (hi/lo split at stage time)
    const int v0 = t, v1 = t + 256;
    const int ln0 = v0 & 63, ln1 = v1 & 63;
    {
        const float* s0 = X + (size_t)(r0 + (v0 >> 8) * 16 + (ln0 & 15)) * DIM +
                          ((v0 >> 6) & 3) * 32 + (ln0 >> 4) * 8;
        bf16x8 hi, lo;
        split8(s0, hi, lo);
        *(bf16x8*)(lds + (v0 >> 6) * 512 + ln0 * 8) = hi;
        *(bf16x8*)(lds + 4096 + (v0 >> 6) * 512 + ln0 * 8) = lo;
    }
    {
        const float* s1 = X + (size_t)(r0 + (v1 >> 8) * 16 + (ln1 & 15)) * DIM +
                          ((v1 >> 6) & 3) * 32 + (ln1 >> 4) * 8;
        bf16x8 hi, lo;
        split8(s1, hi, lo);
        *(bf16x8*)(lds + (v1 >> 6) * 512 + ln1 * 8) = hi;
        *(bf16x8*)(lds + 4096 + (v1 >> 6) * 512 + ln1 * 8) = lo;
    }
    __syncthreads();

    f32x4 acc[2][2];  // [bt][c]
#pragma unroll
    for (int bt = 0; bt < 2; ++bt)
#pragma unroll
        for (int c = 0; c < 2; ++c) acc[bt][c] = (f32x4){0.f, 0.f, 0.f, 0.f};

#pragma unroll
    for (int ks = 0; ks < 4; ++ks) {
#pragma unroll
        for (int bt = 0; bt < 2; ++bt) {
            const int g = bt * 4 + ks;
            const bf16x8 xh = *(const bf16x8*)(lds + g * 512 + lane * 8);
            const bf16x8 xl = *(const bf16x8*)(lds + 4096 + g * 512 + lane * 8);
#pragma unroll
            for (int c = 0; c < 2; ++c) {
                acc[bt][c] = __builtin_amdgcn_mfma_f32_16x16x32_bf16(wh[c][ks], xh, acc[bt][c], 0, 0, 0);
                acc[bt][c] = __builtin_amdgcn_mfma_f32_16x16x32_bf16(wl[c][ks], xh, acc[bt][c], 0, 0, 0);
                acc[bt][c] = __builtin_amdgcn_mfma_f32_16x16x32_bf16(wh[c][ks], xl, acc[bt][c], 0, 0, 0);
            }
        }
    }

    // D: col(m16)=X-row, row(kq*4+reg)=e. Global e = 32*wave+16*c+4*kq ->
    // plane = wave>>1, in-plane col = 32*(wave&1)+16*c+4*kq.
#pragma unroll
    for (int bt = 0; bt < 2; ++bt) {
        const size_t row = (size_t)(r0 + bt * 16 + m16);
#pragma unroll
        for (int c = 0; c < 2; ++c) {
            uint2 w;
            w.x = f2b(acc[bt][c][0]) | (f2b(acc[bt][c][1]) << 16);
            w.y = f2b(acc[bt][c][2]) | (f2b(acc[bt][c][3]) << 16);
            *(uint2*)(C + (size_t)(wave >> 1) * NE2 + row * 64 +
                      (2 * (wave & 1) + c) * 16 + kq * 4) = w;
        }
    }
}

// agg1: H[i] = relu(mean(FW[{i} U adj[i]])); two [N][64] planes (row = one
// 128B line, 16 lanes x uint2 = full-line transactions). At the gather wall.
__global__ __launch_bounds__(256) void agg1(const ushort* __restrict__ FW,
                                            const int* __restrict__ adj,
                                            ushort* __restrict__ H) {
    __shared__ int idx_lds[320];
    const int t = threadIdx.x;
    const int r0 = blockIdx.x * 32;  // 3125 blocks
    for (int l = t; l < 320; l += 256)
        idx_lds[l] = adj[(size_t)r0 * NS + l];  // rows r0..r0+31 contiguous
    __syncthreads();
    const int team = t >> 4;
    const int j = t & 15;
    const int ri0 = team * 2, ri1 = team * 2 + 1;
#pragma unroll
    for (int p = 0; p < 2; ++p) {
        const ushort* FWp = FW + (size_t)p * NE2;
        ushort* Hp = H + (size_t)p * NE2;
        uint2 u0[11], u1[11];
        u0[0] = ((const uint2*)(FWp + (size_t)(r0 + ri0) * 64))[j];
#pragma unroll
        for (int s = 0; s < NS; ++s)
            u0[1 + s] = ((const uint2*)(FWp + (size_t)idx_lds[ri0 * NS + s] * 64))[j];
        u1[0] = ((const uint2*)(FWp + (size_t)(r0 + ri1) * 64))[j];
#pragma unroll
        for (int s = 0; s < NS; ++s)
            u1[1 + s] = ((const uint2*)(FWp + (size_t)idx_lds[ri1 * NS + s] * 64))[j];
        float a0 = 0.f, a1 = 0.f, a2 = 0.f, a3 = 0.f;
        float b0 = 0.f, b1 = 0.f, b2 = 0.f, b3 = 0.f;
#pragma unroll
        for (int s = 0; s < 11; ++s) {
            a0 += bl(u0[s].x); a1 += bl(u0[s].x >> 16);
            a2 += bl(u0[s].y); a3 += bl(u0[s].y >> 16);
            b0 += bl(u1[s].x); b1 += bl(u1[s].x >> 16);
            b2 += bl(u1[s].y); b3 += bl(u1[s].y >> 16);
        }
        uint2 w;
        w.x = f2b(fmaxf(a0 * SCALE, 0.f)) | (f2b(fmaxf(a1 * SCALE, 0.f)) << 16);
        w.y = f2b(fmaxf(a2 * SCALE, 0.f)) | (f2b(fmaxf(a3 * SCALE, 0.f)) << 16);
        ((uint2*)(Hp + (size_t)(r0 + ri0) * 64))[j] = w;
        w.x = f2b(fmaxf(b0 * SCALE, 0.f)) | (f2b(fmaxf(b1 * SCALE, 0.f)) << 16);
        w.y = f2b(fmaxf(b2 * SCALE, 0.f)) | (f2b(fmaxf(b3 * SCALE, 0.f)) << 16);
        ((uint2*)(Hp + (size_t)(r0 + ri1) * 64))[j] = w;
    }
}

// agg2b: P[i] = mean(H[{n} U adj[n]]), n = nodes[i] (no relu). Indices built
// in-kernel via the r7-proven two-stage LDS walk — agg2b runs at high
// occupancy, so the nodes->adj dependent chain hides (unlike inside gemm1).
__global__ __launch_bounds__(256) void agg2b(const ushort* __restrict__ H,
                                             const int* __restrict__ adj,
                                             const int* __restrict__ nodes,
                                             ushort* __restrict__ P) {
    __shared__ int idx_lds[352];
    const int t = threadIdx.x;
    const int r0 = blockIdx.x * 32;  // 3125 blocks
    if (t < 32) idx_lds[t * 11] = nodes[r0 + t];
    __syncthreads();
    for (int l = t; l < 320; l += 256) {
        const int bi = l / 10;
        const int s = l - bi * 10;
        idx_lds[bi * 11 + 1 + s] = adj[(size_t)idx_lds[bi * 11] * NS + s];
    }
    __syncthreads();
    const int team = t >> 4;
    const int j = t & 15;
    const int ri0 = team * 2, ri1 = team * 2 + 1;
#pragma unroll
    for (int p = 0; p < 2; ++p) {
        const ushort* Hp = H + (size_t)p * NE2;
        ushort* Pp = P + (size_t)p * NE2;
        uint2 u0[11], u1[11];
#pragma unroll
        for (int s = 0; s < 11; ++s)
            u0[s] = ((const uint2*)(Hp + (size_t)idx_lds[ri0 * 11 + s] * 64))[j];
#pragma unroll
        for (int s = 0; s < 11; ++s)
            u1[s] = ((const uint2*)(Hp + (size_t)idx_lds[ri1 * 11 + s] * 64))[j];
        float a0 = 0.f, a1 = 0.f, a2 = 0.f, a3 = 0.f;
        float b0 = 0.f, b1 = 0.f, b2 = 0.f, b3 = 0.f;
#pragma unroll
        for (int s = 0; s < 11; ++s) {
            a0 += bl(u0[s].x); a1 += bl(u0[s].x >> 16);
            a2 += bl(u0[s].y); a3 += bl(u0[s].y >> 16);
            b0 += bl(u1[s].x); b1 += bl(u1[s].x >> 16);
            b2 += bl(u1[s].y); b3 += bl(u1[s].y >> 16);
        }
        uint2 w;
        w.x = f2b(a0 * SCALE) | (f2b(a1 * SCALE) << 16);
        w.y = f2b(a2 * SCALE) | (f2b(a3 * SCALE) << 16);
        ((uint2*)(Pp + (size_t)(r0 + ri0) * 64))[j] = w;
        w.x = f2b(b0 * SCALE) | (f2b(b1 * SCALE) << 16);
        w.y = f2b(b2 * SCALE) | (f2b(b3 * SCALE) << 16);
        ((uint2*)(Pp + (size_t)(r0 + ri1) * 64))[j] = w;
    }
}

// gemm2t: out[e][b] = relu(sum_k P[b][k]*W2[e][k]); P from the two 64-col
// planes into LDS fragment layout (linear write, 0 conflicts); W2 split
// in-register (B-operand). acc regs = 4 consecutive b -> float4 stores.
__global__ __launch_bounds__(256, 2) void gemm2t(const ushort* __restrict__ P,
                                                 const float* __restrict__ W2,
                                                 float* __restrict__ out) {
    __shared__ __align__(16) ushort lds[4096];  // 8 groups x 64 lanes x 8 bf16
    const int t = threadIdx.x;
    const int lane = t & 63;
    const int wave = t >> 6;
    const int m16 = lane & 15;
    const int kq = lane >> 4;
    const int r0 = blockIdx.x * 32;

    // slot v: bt=v>>8, ksq=(v>>6)&3, ln=v&63; row=r0+bt*16+(ln&15);
    // k0=ksq*32+(ln>>4)*8 -> plane=ksq>>1, in-plane col=(ksq&1)*32+(ln>>4)*8
#pragma unroll
    for (int i = 0; i < 2; ++i) {
        const int v = t + i * 256;
        const int ln = v & 63;
        const int ksq = (v >> 6) & 3;
        const ushort* s = P + (size_t)(ksq >> 1) * NE2 +
                          (size_t)(r0 + (v >> 8) * 16 + (ln & 15)) * 64 +
                          (ksq & 1) * 32 + (ln >> 4) * 8;
        *(bf16x8*)(lds + (v >> 6) * 512 + ln * 8) = *(const bf16x8*)(s);
    }

    bf16x8 wh[2][4], wl[2][4];
#pragma unroll
    for (int c = 0; c < 2; ++c)
#pragma unroll
        for (int ks = 0; ks < 4; ++ks)
            split8(W2 + (size_t)((2 * wave + c) * 16 + m16) * DIM + ks * 32 + kq * 8,
                   wh[c][ks], wl[c][ks]);
    __syncthreads();

    f32x4 acc[2][2];  // [bt][c]
#pragma unroll
    for (int bt = 0; bt < 2; ++bt)
#pragma unroll
        for (int c = 0; c < 2; ++c) acc[bt][c] = (f32x4){0.f, 0.f, 0.f, 0.f};

#pragma unroll
    for (int ks = 0; ks < 4; ++ks) {
#pragma unroll
        for (int bt = 0; bt < 2; ++bt) {
            const bf16x8 pa = *(const bf16x8*)(lds + (bt * 4 + ks) * 512 + lane * 8);
#pragma unroll
            for (int c = 0; c < 2; ++c) {
                acc[bt][c] = __builtin_amdgcn_mfma_f32_16x16x32_bf16(pa, wh[c][ks], acc[bt][c], 0, 0, 0);
                acc[bt][c] = __builtin_amdgcn_mfma_f32_16x16x32_bf16(pa, wl[c][ks], acc[bt][c], 0, 0, 0);
            }
        }
    }

    // D: col(m16) = e (B-side), row(kq*4+reg) = b (A-side)
#pragma unroll
    for (int bt = 0; bt < 2; ++bt) {
        const int b = r0 + bt * 16 + kq * 4;
#pragma unroll
        for (int c = 0; c < 2; ++c) {
            const int e = (2 * wave + c) * 16 + m16;
            float4 v;
            v.x = fmaxf(acc[bt][c][0], 0.f);
            v.y = fmaxf(acc[bt][c][1], 0.f);
            v.z = fmaxf(acc[bt][c][2], 0.f);
            v.w = fmaxf(acc[bt][c][3], 0.f);
            *(float4*)(out + (size_t)e * N_NODES + b) = v;
        }
    }
}

extern "C" void kernel_launch(void* const* d_in, const int* in_sizes, int n_in,
                              void* d_out, int out_size, void* d_ws, size_t ws_size,
                              hipStream_t stream) {
    const float* features = (const float*)d_in[0];
    const float* W1 = (const float*)d_in[1];
    const float* W2 = (const float*)d_in[2];
    const int* adj = (const int*)d_in[3];
    const int* nodes = (const int*)d_in[4];
    float* out = (float*)d_out;

    const size_t NE = (size_t)N_NODES * DIM;  // 12.8M elems (= 2 planes)
    ushort* fw = (ushort*)d_ws;        // FW1 planes; later reused as P (25.6 MB)
    ushort* h1 = fw + NE;              // h1 planes (25.6 MB)

    // FW1 = features @ W1^T (in-register W split, no extra work)
    gemm1<<<NSTRIP, 256, 0, stream>>>(features, W1, fw);
    // h1 = relu(mean(FW1[self U adj]))
    agg1<<<NSTRIP, 256, 0, stream>>>(fw, adj, h1);
    // P = mean(h1[nodes U adj[nodes]]) (reuses fw buffer)
    agg2b<<<NSTRIP, 256, 0, stream>>>(h1, adj, nodes, fw);
    // out[e][b] = relu(P @ W2^T), coalesced transposed store
    gemm2t<<<NSTRIP, 256, 0, stream>>>(fw, W2, out);
}